// Round 4
// baseline (28.679 us; speedup 1.0000x reference)
//
#include <hip/hip_runtime.h>

// Bicubic resize (align_corners=True, PyTorch a=-0.75) from (N=4096, 224, 224)
// to (12, 52), fused with ReLU.
//
// R3 changes vs R2:
//  - Each wave handles TWO planes (same oh): weight/index math amortized 2x,
//    8 outstanding loads per wave instead of 4 (deeper memory-level
//    parallelism), half the wave count. Total HBM bytes unchanged.

#define A_COEF (-0.75f)
#define IN_H 224
#define IN_W 224
#define OUT_H 12
#define OUT_W 52

// 16-byte load with only 4-byte alignment guarantee (window start arbitrary).
struct __attribute__((packed, aligned(4))) f4u { float a, b, c, d; };

__device__ __forceinline__ float w_near(float s) {
    return ((A_COEF + 2.0f) * s - (A_COEF + 3.0f)) * s * s + 1.0f;
}
__device__ __forceinline__ float w_far(float s) {
    return A_COEF * (((s - 5.0f) * s + 8.0f) * s - 4.0f);
}

__global__ __launch_bounds__(256) void bicubic_relu_kernel(
        const float* __restrict__ x, float* __restrict__ out) {
    int lane = threadIdx.x & 63;
    int gw   = blockIdx.x * 4 + (threadIdx.x >> 6);  // 0..24575
    int oh     = gw % OUT_H;
    int pair   = gw / OUT_H;
    int plane0 = pair * 2;
    if (lane >= OUT_W) return;
    int ow = lane;

    // ---- W taps: contiguous window [wbase, wbase+3] + 4 weights ----
    int wbase;
    float ww0, ww1, ww2, ww3;
    if (ow == 0) {                     // t==0 exactly: only col 0
        wbase = 0;
        ww0 = 1.0f; ww1 = 0.0f; ww2 = 0.0f; ww3 = 0.0f;
    } else if (ow == OUT_W - 1) {      // t==0 exactly: only col 223
        wbase = IN_W - 4;
        ww0 = 0.0f; ww1 = 0.0f; ww2 = 0.0f; ww3 = 1.0f;
    } else {                           // interior: window within [3, 220]
        float srcw = ((float)(ow * (IN_W - 1))) / (float)(OUT_W - 1);
        int   w0   = (int)floorf(srcw);
        float tw   = srcw - (float)w0;
        wbase = w0 - 1;
        ww0 = w_far(1.0f + tw);
        ww1 = w_near(tw);
        ww2 = w_near(1.0f - tw);
        ww3 = w_far(2.0f - tw);
    }

    const size_t plane_sz = (size_t)(IN_H * IN_W);
    const float* p0 = x + (size_t)plane0 * plane_sz + wbase;
    const float* p1 = p0 + plane_sz;

    float acc0, acc1;

    if (oh == 0 || oh == OUT_H - 1) {
        // Wave-uniform: single row with weight 1 -> one load per plane.
        int row = (oh == 0) ? 0 : (IN_H - 1);
        f4u q0 = *reinterpret_cast<const f4u*>(p0 + row * IN_W);
        f4u q1 = *reinterpret_cast<const f4u*>(p1 + row * IN_W);
        float r0 = ww0 * q0.a;
        r0 = fmaf(ww1, q0.b, r0);
        r0 = fmaf(ww2, q0.c, r0);
        acc0 = fmaf(ww3, q0.d, r0);
        float r1 = ww0 * q1.a;
        r1 = fmaf(ww1, q1.b, r1);
        r1 = fmaf(ww2, q1.c, r1);
        acc1 = fmaf(ww3, q1.d, r1);
    } else {
        float srch = ((float)(oh * (IN_H - 1))) / (float)(OUT_H - 1);
        int   h0   = (int)floorf(srch);
        float th   = srch - (float)h0;
        float wh[4] = { w_far(1.0f + th), w_near(th),
                        w_near(1.0f - th), w_far(2.0f - th) };
        // Issue all 8 loads first (deep MLP), then reduce.
        f4u q0[4], q1[4];
        #pragma unroll
        for (int j = 0; j < 4; ++j) {
            q0[j] = *reinterpret_cast<const f4u*>(p0 + (h0 - 1 + j) * IN_W);
            q1[j] = *reinterpret_cast<const f4u*>(p1 + (h0 - 1 + j) * IN_W);
        }
        acc0 = 0.0f; acc1 = 0.0f;
        #pragma unroll
        for (int j = 0; j < 4; ++j) {
            float r0 = ww0 * q0[j].a;
            r0 = fmaf(ww1, q0[j].b, r0);
            r0 = fmaf(ww2, q0[j].c, r0);
            r0 = fmaf(ww3, q0[j].d, r0);
            acc0 = fmaf(wh[j], r0, acc0);
            float r1 = ww0 * q1[j].a;
            r1 = fmaf(ww1, q1[j].b, r1);
            r1 = fmaf(ww2, q1[j].c, r1);
            r1 = fmaf(ww3, q1[j].d, r1);
            acc1 = fmaf(wh[j], r1, acc1);
        }
    }

    size_t o0 = ((size_t)plane0 * OUT_H + oh) * OUT_W + ow;
    out[o0]                  = fmaxf(acc0, 0.0f);
    out[o0 + OUT_H * OUT_W]  = fmaxf(acc1, 0.0f);
}

extern "C" void kernel_launch(void* const* d_in, const int* in_sizes, int n_in,
                              void* d_out, int out_size, void* d_ws, size_t ws_size,
                              hipStream_t stream) {
    const float* x = (const float*)d_in[0];
    float* out = (float*)d_out;
    // 2048 plane-pairs * 12 oh = 24576 waves; 4 waves per 256-thread block.
    int blocks = (2048 * OUT_H) / 4;  // 6144
    bicubic_relu_kernel<<<blocks, 256, 0, stream>>>(x, out);
}